// Round 13
// baseline (71.451 us; speedup 1.0000x reference)
//
#include <hip/hip_runtime.h>

#define BATCH 8192
#define DIM   512
#define NBLK  2080                 // 64x64 grid of 128^2 tiles, bi <= bj

typedef __attribute__((ext_vector_type(4))) int   int4v;
typedef __attribute__((ext_vector_type(8))) int   int8v;
typedef __attribute__((ext_vector_type(4))) float f32x4;
typedef unsigned char u8;

// async global->LDS, 16B per lane; LDS dest = wave-uniform base + lane*16
__device__ __forceinline__ void gload_lds16(const void* g, void* l){
  __builtin_amdgcn_global_load_lds(
      (const __attribute__((address_space(1))) void*)g,
      (__attribute__((address_space(3))) void*)l, 16, 0, 0);
}

// VALU-only 16-lane-group sum via DPP (verified r7-r12)
template<int CTRL>
__device__ __forceinline__ float dpp_add(float v){
  int s = __builtin_amdgcn_update_dpp(0, __float_as_int(v), CTRL, 0xF, 0xF, true);
  return v + __int_as_float(s);
}
__device__ __forceinline__ float red16(float v){
  v = dpp_add<0xB1>(v);    // quad_perm [1,0,3,2]
  v = dpp_add<0x4E>(v);    // quad_perm [2,3,0,1]
  v = dpp_add<0x141>(v);   // row_half_mirror
  v = dpp_add<0x140>(v);   // row_mirror
  return v;
}

// f32 -> OCP e4m3fn, RTNE, |v| <= 1 (unit-norm rows) (verified r8)
__device__ __forceinline__ u8 f2e4m3(float v){
  unsigned s = (__float_as_uint(v) >> 24) & 0x80u;
  float a = fabsf(v);
  if (a < 0.0009765625f) return (u8)s;
  if (a < 0.015625f){
    int qd = (int)rintf(a * 512.0f);
    return (u8)(s | (unsigned)qd);
  }
  unsigned u = __float_as_uint(a);
  int E = (int)(u >> 23) - 127;
  unsigned m = u & 0x7FFFFF;
  unsigned mant = m >> 20;
  unsigned rem  = m & 0xFFFFF;
  mant += (rem > 0x80000u || (rem == 0x80000u && (mant & 1u))) ? 1u : 0u;
  if (mant == 8u){ mant = 0u; E += 1; }
  return (u8)(s | ((unsigned)(E + 7) << 3) | mant);
}

// --- Kernel 1: L2-normalize rows -> fp8 e4m3, K-contiguous swizzle ----------
// Per row, 64B unit kb = 4 logical 16B chunks l (K bytes [16l,16l+16));
// chunk l stored at phys l ^ ((row>>1)&3) ^ (kb&1).  The kb-parity term makes
// even/odd-granule readers in k_gemm hit disjoint chunk positions (conflict
// fix vs r12). k_gemm stages linearly and reads with the same XOR.
__global__ __launch_bounds__(256) void k_normalize(const float* __restrict__ x,
                                                   u8* __restrict__ q){
  const int row  = blockIdx.x * 4 + (threadIdx.x >> 6);
  const int lane = threadIdx.x & 63;
  const float* xr = x + (size_t)row * DIM + lane * 8;
  float4 a = *(const float4*)xr;
  float4 b = *(const float4*)(xr + 4);
  float s = a.x*a.x + a.y*a.y + a.z*a.z + a.w*a.w
          + b.x*b.x + b.y*b.y + b.z*b.z + b.w*b.w;
  #pragma unroll
  for (int m = 1; m < 64; m <<= 1) s += __shfl_xor(s, m);
  const float inv = 1.0f / fmaxf(sqrtf(s), 1e-12f);
  float f[8] = {a.x, a.y, a.z, a.w, b.x, b.y, b.z, b.w};
  union { u8 b[8]; unsigned long long u; } pk;
  #pragma unroll
  for (int e = 0; e < 8; e++) pk.b[e] = f2e4m3(f[e] * inv);
  const int kb = lane >> 3;                 // 64B unit 0..7
  const int g  = lane & 7;                  // 8B group within unit
  const int sw = (row >> 1) & 3;
  const size_t off = (size_t)row * DIM + kb * 64
                   + (size_t)((((g >> 1) ^ sw ^ (kb & 1)) & 3) * 16 + (g & 1) * 8);
  *(unsigned long long*)(q + off) = pk.u;
}

// --- Kernel 2: fp8 GEMM via MX-scaled 16x16x128 MFMA (scale = 2^0) ----------
// 128x128 tiles, 4 waves (2x2), wave tile 64x64 = 4x4 frags. Ring-3 8KB
// granules (48KB -> 3 blk/CU). Iteration u consumes K-tile pair (2u,2u+1);
// lane quarter g reads global K [128u+32g, +32) = 2 b128 from granule
// (2u + (g>>3? no: g>>1)), phys chunks (2(g&1))^sw^bufsel and ^1.
// Arithmetic identical to non-scaled fp8 (r12: absmax 0.0). Register-
// pressure fix vs r12: bv handled in two 2-frag halves (16 regs reused),
// second MFMA half register-only after staging.
__global__ __launch_bounds__(256, 3) void k_gemm(const u8* __restrict__ q,
                                                 const int* __restrict__ labels,
                                                 float* __restrict__ ppos,
                                                 float* __restrict__ ptot){
  __shared__ u8 sA[3][128 * 64];    // 3 x 8 KB
  __shared__ u8 sB[3][128 * 64];    // 3 x 8 KB
  __shared__ int labI[128], labJ[128];

  // XCD swizzle (2080 = 8 x 260, bijective) + triangular decode (r2-verified)
  const int bid = (blockIdx.x & 7) * 260 + (blockIdx.x >> 3);
  int bj = (int)((sqrtf(8.0f * (float)bid + 1.0f) - 1.0f) * 0.5f);
  while ((bj + 1) * (bj + 2) / 2 <= bid) bj++;
  while (bj * (bj + 1) / 2 > bid) bj--;
  const int bi = bid - bj * (bj + 1) / 2;
  const bool mirror = (bi != bj);
  const int rowbase = bi * 128, colbase = bj * 128;

  const int t    = threadIdx.x;
  const int lane = t & 63;
  const int w    = t >> 6;
  const int wr   = w >> 1, wc = w & 1;
  const int lrow = lane & 15;
  const int g    = lane >> 4;           // k-quarter 0..3
  const int bufsel = g >> 1;            // 0: even K-tile, 1: odd K-tile

  if (t < 128) labI[t] = labels[rowbase + t];
  else         labJ[t - 128] = labels[colbase + (t - 128)];

  // frag byte offsets: row*64 + phys_chunk*16; phys = (2(g&1))^sw^bufsel,
  // second b128 at ^16 (phys^1). Involution matches k_normalize.
  const int sw = (lrow >> 1) & 3;
  const int ph = ((((g & 1) * 2) ^ sw ^ bufsel) & 3) * 16;
  int ra[4], rb[4];
  #pragma unroll
  for (int m = 0; m < 4; m++) ra[m] = (wr * 64 + m * 16 + lrow) * 64 + ph;
  #pragma unroll
  for (int n = 0; n < 4; n++) rb[n] = (wc * 64 + n * 16 + lrow) * 64 + ph;

  // staging: thread t covers row (t>>2) (+64/shot), phys chunk16 (t&3)
  const u8* srcA = q + (size_t)(rowbase + (t >> 2)) * DIM + (t & 3) * 16;
  const u8* srcB = q + (size_t)(colbase + (t >> 2)) * DIM + (t & 3) * 16;
  const int dL = t * 16;

#define STAGE(BUF, KT) do{                                                \
    gload_lds16(srcA + (KT) * 64,             sA[BUF] + dL);              \
    gload_lds16(srcA + (KT) * 64 + 64 * DIM,  sA[BUF] + dL + 4096);       \
    gload_lds16(srcB + (KT) * 64,             sB[BUF] + dL);              \
    gload_lds16(srcB + (KT) * 64 + 64 * DIM,  sB[BUF] + dL + 4096);       \
  }while(0)
#define RD(DST, P, RO) do{                                                \
    int4v lo_ = *(const int4v*)((P) + (RO));                              \
    int4v hi_ = *(const int4v*)((P) + ((RO) ^ 16));                       \
    DST = __builtin_shufflevector(lo_, hi_, 0, 1, 2, 3, 4, 5, 6, 7);      \
  }while(0)

  f32x4 acc[4][4];
  #pragma unroll
  for (int m = 0; m < 4; m++)
    #pragma unroll
    for (int n = 0; n < 4; n++)
      acc[m][n] = (f32x4){0.f, 0.f, 0.f, 0.f};

  // prologue: labels + stage K-tiles 0,1
  STAGE(0, 0);
  STAGE(1, 1);
  __syncthreads();

  #pragma unroll
  for (int u = 0; u < 4; ++u){
    const int b_lo = (2 * u) % 3;
    const int b_hi = (2 * u + 1) % 3;
    const int b_nx = (2 * u + 2) % 3;
    const u8* pA = bufsel ? sA[b_hi] : sA[b_lo];
    const u8* pB = bufsel ? sB[b_hi] : sB[b_lo];

    int8v av[4], bvx[2];
    #pragma unroll
    for (int m = 0; m < 4; m++) RD(av[m], pA, ra[m]);
    #pragma unroll
    for (int n = 0; n < 2; n++) RD(bvx[n], pB, rb[n]);
    __builtin_amdgcn_s_setprio(1);
    #pragma unroll
    for (int m = 0; m < 4; m++)
      #pragma unroll
      for (int n = 0; n < 2; n++)
        acc[m][n] = __builtin_amdgcn_mfma_scale_f32_16x16x128_f8f6f4(
            av[m], bvx[n], acc[m][n], 0, 0, 0, 127, 0, 127);
    __builtin_amdgcn_s_setprio(0);
    #pragma unroll
    for (int n = 0; n < 2; n++) RD(bvx[n], pB, rb[2 + n]);   // reuse regs
    __syncthreads();                      // all reads done before overwrite
    if (u < 3){ STAGE(b_nx, 2 * u + 2); STAGE(b_lo, 2 * u + 3); }
    __builtin_amdgcn_s_setprio(1);
    #pragma unroll
    for (int m = 0; m < 4; m++)
      #pragma unroll
      for (int n = 0; n < 2; n++)
        acc[m][2 + n] = __builtin_amdgcn_mfma_scale_f32_16x16x128_f8f6f4(
            av[m], bvx[n], acc[m][2 + n], 0, 0, 0, 127, 0, 127);
    __builtin_amdgcn_s_setprio(0);
    __syncthreads();                      // next pair staged & visible
  }
#undef STAGE
#undef RD

  const int i0 = rowbase + wr * 64;
  const int j0 = colbase + wc * 64;

  int lj_[4];
  #pragma unroll
  for (int n = 0; n < 4; n++)
    lj_[n] = labJ[wc * 64 + n * 16 + lrow];

  const float invT = 14.285714285714286f;  // 1/0.07
  #pragma unroll
  for (int m = 0; m < 4; m++)
    #pragma unroll
    for (int n = 0; n < 4; n++)
      #pragma unroll
      for (int e = 0; e < 4; e++){
        int i = i0 + m * 16 + g * 4 + e;
        int j = j0 + n * 16 + lrow;
        acc[m][n][e] = (i == j) ? 0.0f : __expf(acc[m][n][e] * invT);
      }

  // row sums -> slot 2*bj + wc (DPP reduce, VALU-only); labels from LDS per m
  {
    float* pp = ppos + (size_t)(2 * bj + wc) * BATCH;
    float* pt = ptot + (size_t)(2 * bj + wc) * BATCH;
    #pragma unroll
    for (int m = 0; m < 4; m++){
      int li4[4];
      #pragma unroll
      for (int e = 0; e < 4; e++) li4[e] = labI[wr * 64 + m * 16 + g * 4 + e];
      float tr[4] = {0, 0, 0, 0}, pr[4] = {0, 0, 0, 0};
      #pragma unroll
      for (int n = 0; n < 4; n++){
        int lj = lj_[n];
        #pragma unroll
        for (int e = 0; e < 4; e++){
          float v = acc[m][n][e];
          tr[e] += v;
          pr[e] += (li4[e] == lj) ? v : 0.0f;
        }
      }
      #pragma unroll
      for (int e = 0; e < 4; e++){
        tr[e] = red16(tr[e]);
        pr[e] = red16(pr[e]);
      }
      if (lrow == 0){
        int ib = i0 + m * 16 + g * 4;
        #pragma unroll
        for (int e = 0; e < 4; e++){
          pt[ib + e] = tr[e];
          pp[ib + e] = pr[e];
        }
      }
    }
  }

  // col sums via symmetry -> slot 2*bi + wr
  if (mirror){
    float* pp = ppos + (size_t)(2 * bi + wr) * BATCH;
    float* pt = ptot + (size_t)(2 * bi + wr) * BATCH;
    #pragma unroll
    for (int n = 0; n < 4; n++){
      float ts = 0.f, ps = 0.f;
      int lj = lj_[n];
      #pragma unroll
      for (int m = 0; m < 4; m++){
        int li4[4];
        #pragma unroll
        for (int e = 0; e < 4; e++) li4[e] = labI[wr * 64 + m * 16 + g * 4 + e];
        #pragma unroll
        for (int e = 0; e < 4; e++){
          float v = acc[m][n][e];
          ts += v;
          ps += (li4[e] == lj) ? v : 0.0f;
        }
      }
      ts += __shfl_xor(ts, 16); ps += __shfl_xor(ps, 16);
      ts += __shfl_xor(ts, 32); ps += __shfl_xor(ps, 32);
      if (lane < 16){
        int j = j0 + n * 16 + lane;
        pt[j] = ts;
        pp[j] = ps;
      }
    }
  }
}

// --- Kernel 3: per-row loss, 256 blocks (32 rows each), coalesced -----------
__global__ __launch_bounds__(256) void k_rowloss(const float* __restrict__ ppos,
                                                 const float* __restrict__ ptot,
                                                 float* __restrict__ bsum){
  __shared__ float sp[256], st2[256];
  const int t = threadIdx.x;
  const int r = blockIdx.x * 32 + (t & 31);
  const int c0 = t >> 5;                      // 0..7
  float p = 0.f, tt = 0.f;
  for (int c = c0; c < 128; c += 8){
    p  += ppos[(size_t)c * BATCH + r];
    tt += ptot[(size_t)c * BATCH + r];
  }
  sp[t] = p; st2[t] = tt;
  __syncthreads();
  if (t < 32){
    float P = 0.f, T = 0.f;
    #pragma unroll
    for (int k = 0; k < 8; k++){ P += sp[t + k * 32]; T += st2[t + k * 32]; }
    sp[t] = -logf(P / (T + 1e-8f));
  }
  __syncthreads();
  if (t == 0){
    float s = 0.f;
    #pragma unroll
    for (int k = 0; k < 32; k++) s += sp[k];
    bsum[blockIdx.x] = s;
  }
}

// --- Kernel 4: final mean over 256 block sums -------------------------------
__global__ __launch_bounds__(256) void k_final(const float* __restrict__ bsum,
                                               float* __restrict__ out){
  __shared__ float s4[4];
  float v = bsum[threadIdx.x];
  #pragma unroll
  for (int m = 1; m < 64; m <<= 1) v += __shfl_xor(v, m);
  if ((threadIdx.x & 63) == 0) s4[threadIdx.x >> 6] = v;
  __syncthreads();
  if (threadIdx.x == 0) out[0] = (s4[0] + s4[1] + s4[2] + s4[3]) * (1.0f / 8192.0f);
}

extern "C" void kernel_launch(void* const* d_in, const int* in_sizes, int n_in,
                              void* d_out, int out_size, void* d_ws, size_t ws_size,
                              hipStream_t stream){
  const float* x      = (const float*)d_in[0];
  const int*   labels = (const int*)d_in[1];
  float*       out    = (float*)d_out;

  char* ws = (char*)d_ws;
  u8*    q    = (u8*)ws;                             //  4,194,304 B (8192x512 fp8)
  float* ppos = (float*)(ws + 8388608);              //  4,194,304 B (128 x 8192 f32)
  float* ptot = (float*)(ws + 8388608 + 4194304);    //  4,194,304 B
  float* bsum = (float*)(ws + 8388608 + 8388608);    //      1,024 B

  k_normalize<<<BATCH / 4, 256, 0, stream>>>(x, q);
  k_gemm<<<NBLK, 256, 0, stream>>>(q, labels, ppos, ptot);
  k_rowloss<<<256, 256, 0, stream>>>(ppos, ptot, bsum);
  k_final<<<1, 256, 0, stream>>>(bsum, out);
}

// Round 14
// 55.665 us; speedup vs baseline: 1.2836x; 1.2836x over previous
//
#include <hip/hip_runtime.h>

#define BATCH 8192
#define DIM   512
#define NBLK  2080                 // 64x64 grid of 128^2 tiles, bi <= bj

typedef __attribute__((ext_vector_type(2))) long long2_t;
typedef __attribute__((ext_vector_type(4))) float f32x4;
typedef unsigned char u8;

// async global->LDS, 16B per lane; LDS dest = wave-uniform base + lane*16
__device__ __forceinline__ void gload_lds16(const void* g, void* l){
  __builtin_amdgcn_global_load_lds(
      (const __attribute__((address_space(1))) void*)g,
      (__attribute__((address_space(3))) void*)l, 16, 0, 0);
}

// VALU-only 16-lane-group sum via DPP (verified r7-r9)
template<int CTRL>
__device__ __forceinline__ float dpp_add(float v){
  int s = __builtin_amdgcn_update_dpp(0, __float_as_int(v), CTRL, 0xF, 0xF, true);
  return v + __int_as_float(s);
}
__device__ __forceinline__ float red16(float v){
  v = dpp_add<0xB1>(v);    // quad_perm [1,0,3,2]
  v = dpp_add<0x4E>(v);    // quad_perm [2,3,0,1]
  v = dpp_add<0x141>(v);   // row_half_mirror
  v = dpp_add<0x140>(v);   // row_mirror
  return v;
}

// f32 -> OCP e4m3fn, RTNE, |v| <= 1 (unit-norm rows) (verified r8)
__device__ __forceinline__ u8 f2e4m3(float v){
  unsigned s = (__float_as_uint(v) >> 24) & 0x80u;
  float a = fabsf(v);
  if (a < 0.0009765625f) return (u8)s;
  if (a < 0.015625f){
    int qd = (int)rintf(a * 512.0f);
    return (u8)(s | (unsigned)qd);
  }
  unsigned u = __float_as_uint(a);
  int E = (int)(u >> 23) - 127;
  unsigned m = u & 0x7FFFFF;
  unsigned mant = m >> 20;
  unsigned rem  = m & 0xFFFFF;
  mant += (rem > 0x80000u || (rem == 0x80000u && (mant & 1u))) ? 1u : 0u;
  if (mant == 8u){ mant = 0u; E += 1; }
  return (u8)(s | ((unsigned)(E + 7) << 3) | mant);
}

// --- Kernel 1: L2-normalize rows -> fp8 e4m3, pre-swizzled layout (r8/r9) ---
__global__ __launch_bounds__(256) void k_normalize(const float* __restrict__ x,
                                                   u8* __restrict__ q){
  const int row  = blockIdx.x * 4 + (threadIdx.x >> 6);
  const int lane = threadIdx.x & 63;
  const float* xr = x + (size_t)row * DIM + lane * 8;
  float4 a = *(const float4*)xr;
  float4 b = *(const float4*)(xr + 4);
  float s = a.x*a.x + a.y*a.y + a.z*a.z + a.w*a.w
          + b.x*b.x + b.y*b.y + b.z*b.z + b.w*b.w;
  #pragma unroll
  for (int m = 1; m < 64; m <<= 1) s += __shfl_xor(s, m);
  const float inv = 1.0f / fmaxf(sqrtf(s), 1e-12f);
  float f[8] = {a.x, a.y, a.z, a.w, b.x, b.y, b.z, b.w};
  union { u8 b[8]; unsigned long long u; } pk;
  #pragma unroll
  for (int e = 0; e < 8; e++) pk.b[e] = f2e4m3(f[e] * inv);
  const int kb = lane >> 3;                 // BK-unit 0..7
  const int g  = lane & 7;                  // logical 8B k-group
  const int sw = (row >> 1) & 3;
  const size_t off = (size_t)row * DIM + kb * 64
                   + (size_t)(((g & 3) ^ sw) * 16 + (g >> 2) * 8);
  *(unsigned long long*)(q + off) = pk.u;
}

// --- Kernel 2: fp8 GEMM, 128x128 tiles, 3 blocks/CU (r9, measured 42.1us) ---
// 4 waves (2x2), wave tile 64x64 = 4x4 frags of 16x16x32 fp8 (one b128
// ds_read per frag feeds both k-halves). BK=64 dbuf (32KB). 2080 tiles /
// 768 slots = 2.71 rounds. Slots (r2/r3-verified algebra): row path 2*bj+wc
// covers [2*bi,128); mirror (bi<bj) 2*bi+wr covers [0,2*bj) -> complete,
// write-once, deterministic.
__global__ __launch_bounds__(256, 3) void k_gemm(const u8* __restrict__ q,
                                                 const int* __restrict__ labels,
                                                 float* __restrict__ ppos,
                                                 float* __restrict__ ptot){
  __shared__ u8 sA[2][128 * 64];    // 2 x 8 KB
  __shared__ u8 sB[2][128 * 64];    // 2 x 8 KB
  __shared__ int labI[128], labJ[128];

  // XCD swizzle (2080 = 8 x 260, bijective) + triangular decode (r2-verified)
  const int bid = (blockIdx.x & 7) * 260 + (blockIdx.x >> 3);
  int bj = (int)((sqrtf(8.0f * (float)bid + 1.0f) - 1.0f) * 0.5f);
  while ((bj + 1) * (bj + 2) / 2 <= bid) bj++;
  while (bj * (bj + 1) / 2 > bid) bj--;
  const int bi = bid - bj * (bj + 1) / 2;
  const bool mirror = (bi != bj);
  const int rowbase = bi * 128, colbase = bj * 128;

  const int t    = threadIdx.x;
  const int lane = t & 63;
  const int w    = t >> 6;
  const int wr   = w >> 1, wc = w & 1;
  const int lrow = lane & 15;
  const int g    = lane >> 4;

  if (t < 128) labI[t] = labels[rowbase + t];
  else         labJ[t - 128] = labels[colbase + (t - 128)];

  // swizzled chunk16 byte offset within a 64B row-unit (r8-verified)
  const int gs = (g ^ ((lrow >> 1) & 3)) * 16;
  int ra[4], rb[4];
  #pragma unroll
  for (int m = 0; m < 4; m++) ra[m] = (wr * 64 + m * 16 + lrow) * 64 + gs;
  #pragma unroll
  for (int n = 0; n < 4; n++) rb[n] = (wc * 64 + n * 16 + lrow) * 64 + gs;

  // staging: thread t covers row (t>>2) (+64/shot), phys chunk16 (t&3)
  const u8* srcA = q + (size_t)(rowbase + (t >> 2)) * DIM + (t & 3) * 16;
  const u8* srcB = q + (size_t)(colbase + (t >> 2)) * DIM + (t & 3) * 16;
  const int dL = t * 16;

#define STAGE(BUF, KT) do{                                                \
    gload_lds16(srcA + (KT) * 64,             sA[BUF] + dL);              \
    gload_lds16(srcA + (KT) * 64 + 64 * DIM,  sA[BUF] + dL + 4096);       \
    gload_lds16(srcB + (KT) * 64,             sB[BUF] + dL);              \
    gload_lds16(srcB + (KT) * 64 + 64 * DIM,  sB[BUF] + dL + 4096);       \
  }while(0)

  f32x4 acc[4][4];
  #pragma unroll
  for (int m = 0; m < 4; m++)
    #pragma unroll
    for (int n = 0; n < 4; n++)
      acc[m][n] = (f32x4){0.f, 0.f, 0.f, 0.f};

  STAGE(0, 0);
  __syncthreads();

  for (int kt = 0; kt < 8; ++kt){
    const int cur = kt & 1;
    if (kt < 7) STAGE(cur ^ 1, kt + 1);        // issue next tile early
    const u8* pA = sA[cur];
    const u8* pB = sB[cur];
    long2_t av[4], bv[4];
    #pragma unroll
    for (int n = 0; n < 4; n++) bv[n] = *(const long2_t*)(pB + rb[n]);
    #pragma unroll
    for (int m = 0; m < 4; m++) av[m] = *(const long2_t*)(pA + ra[m]);
    #pragma unroll
    for (int m = 0; m < 4; m++)
      #pragma unroll
      for (int n = 0; n < 4; n++)
        acc[m][n] = __builtin_amdgcn_mfma_f32_16x16x32_fp8_fp8(
            av[m][0], bv[n][0], acc[m][n], 0, 0, 0);
    #pragma unroll
    for (int m = 0; m < 4; m++)
      #pragma unroll
      for (int n = 0; n < 4; n++)
        acc[m][n] = __builtin_amdgcn_mfma_f32_16x16x32_fp8_fp8(
            av[m][1], bv[n][1], acc[m][n], 0, 0, 0);
    __syncthreads();                           // drains vmcnt (loads ~1 tile old)
  }
#undef STAGE

  const int i0 = rowbase + wr * 64;
  const int j0 = colbase + wc * 64;

  int li_[4][4], lj_[4];
  #pragma unroll
  for (int m = 0; m < 4; m++)
    #pragma unroll
    for (int e = 0; e < 4; e++)
      li_[m][e] = labI[wr * 64 + m * 16 + g * 4 + e];
  #pragma unroll
  for (int n = 0; n < 4; n++)
    lj_[n] = labJ[wc * 64 + n * 16 + lrow];

  const float invT = 14.285714285714286f;  // 1/0.07
  #pragma unroll
  for (int m = 0; m < 4; m++)
    #pragma unroll
    for (int n = 0; n < 4; n++)
      #pragma unroll
      for (int e = 0; e < 4; e++){
        int i = i0 + m * 16 + g * 4 + e;
        int j = j0 + n * 16 + lrow;
        acc[m][n][e] = (i == j) ? 0.0f : __expf(acc[m][n][e] * invT);
      }

  // row sums -> slot 2*bj + wc (DPP reduce, VALU-only)
  {
    float* pp = ppos + (size_t)(2 * bj + wc) * BATCH;
    float* pt = ptot + (size_t)(2 * bj + wc) * BATCH;
    #pragma unroll
    for (int m = 0; m < 4; m++){
      float tr[4] = {0, 0, 0, 0}, pr[4] = {0, 0, 0, 0};
      #pragma unroll
      for (int n = 0; n < 4; n++){
        int lj = lj_[n];
        #pragma unroll
        for (int e = 0; e < 4; e++){
          float v = acc[m][n][e];
          tr[e] += v;
          pr[e] += (li_[m][e] == lj) ? v : 0.0f;
        }
      }
      #pragma unroll
      for (int e = 0; e < 4; e++){
        tr[e] = red16(tr[e]);
        pr[e] = red16(pr[e]);
      }
      if (lrow == 0){
        int ib = i0 + m * 16 + g * 4;
        #pragma unroll
        for (int e = 0; e < 4; e++){
          pt[ib + e] = tr[e];
          pp[ib + e] = pr[e];
        }
      }
    }
  }

  // col sums via symmetry -> slot 2*bi + wr
  if (mirror){
    float* pp = ppos + (size_t)(2 * bi + wr) * BATCH;
    float* pt = ptot + (size_t)(2 * bi + wr) * BATCH;
    #pragma unroll
    for (int n = 0; n < 4; n++){
      float ts = 0.f, ps = 0.f;
      int lj = lj_[n];
      #pragma unroll
      for (int m = 0; m < 4; m++)
        #pragma unroll
        for (int e = 0; e < 4; e++){
          float v = acc[m][n][e];
          ts += v;
          ps += (li_[m][e] == lj) ? v : 0.0f;
        }
      ts += __shfl_xor(ts, 16); ps += __shfl_xor(ps, 16);
      ts += __shfl_xor(ts, 32); ps += __shfl_xor(ps, 32);
      if (lane < 16){
        int j = j0 + n * 16 + lane;
        pt[j] = ts;
        pp[j] = ps;
      }
    }
  }
}

// --- Kernel 3: per-row loss, 256 blocks (32 rows each), coalesced -----------
__global__ __launch_bounds__(256) void k_rowloss(const float* __restrict__ ppos,
                                                 const float* __restrict__ ptot,
                                                 float* __restrict__ bsum){
  __shared__ float sp[256], st2[256];
  const int t = threadIdx.x;
  const int r = blockIdx.x * 32 + (t & 31);
  const int c0 = t >> 5;                      // 0..7
  float p = 0.f, tt = 0.f;
  for (int c = c0; c < 128; c += 8){
    p  += ppos[(size_t)c * BATCH + r];
    tt += ptot[(size_t)c * BATCH + r];
  }
  sp[t] = p; st2[t] = tt;
  __syncthreads();
  if (t < 32){
    float P = 0.f, T = 0.f;
    #pragma unroll
    for (int k = 0; k < 8; k++){ P += sp[t + k * 32]; T += st2[t + k * 32]; }
    sp[t] = -logf(P / (T + 1e-8f));
  }
  __syncthreads();
  if (t == 0){
    float s = 0.f;
    #pragma unroll
    for (int k = 0; k < 32; k++) s += sp[k];
    bsum[blockIdx.x] = s;
  }
}

// --- Kernel 4: final mean over 256 block sums -------------------------------
__global__ __launch_bounds__(256) void k_final(const float* __restrict__ bsum,
                                               float* __restrict__ out){
  __shared__ float s4[4];
  float v = bsum[threadIdx.x];
  #pragma unroll
  for (int m = 1; m < 64; m <<= 1) v += __shfl_xor(v, m);
  if ((threadIdx.x & 63) == 0) s4[threadIdx.x >> 6] = v;
  __syncthreads();
  if (threadIdx.x == 0) out[0] = (s4[0] + s4[1] + s4[2] + s4[3]) * (1.0f / 8192.0f);
}

extern "C" void kernel_launch(void* const* d_in, const int* in_sizes, int n_in,
                              void* d_out, int out_size, void* d_ws, size_t ws_size,
                              hipStream_t stream){
  const float* x      = (const float*)d_in[0];
  const int*   labels = (const int*)d_in[1];
  float*       out    = (float*)d_out;

  char* ws = (char*)d_ws;
  u8*    q    = (u8*)ws;                             //  4,194,304 B (8192x512 fp8)
  float* ppos = (float*)(ws + 8388608);              //  4,194,304 B (128 x 8192 f32)
  float* ptot = (float*)(ws + 8388608 + 4194304);    //  4,194,304 B
  float* bsum = (float*)(ws + 8388608 + 8388608);    //      1,024 B

  k_normalize<<<BATCH / 4, 256, 0, stream>>>(x, q);
  k_gemm<<<NBLK, 256, 0, stream>>>(q, labels, ppos, ptot);
  k_rowloss<<<256, 256, 0, stream>>>(ppos, ptot, bsum);
  k_final<<<1, 256, 0, stream>>>(bsum, out);
}